// Round 2
// baseline (232.205 us; speedup 1.0000x reference)
//
#include <hip/hip_runtime.h>

#define G_ 100
#define T_ 24
#define GP1 101            // G + 1 (slack appended)
#define BPB 4              // b's per block (each block does BOTH passes)
#define BLOCK (2 * BPB * T_)  // 192 threads: tid = pass*96 + bb*24 + t

// Batched merit-order chunk: N address-independent loads first (N outstanding
// global loads -> MLP), then the serial clip-scan + stores.
template<int N>
__device__ __forceinline__ void chunk(int k0,
    const float* __restrict__ Rbt, float* __restrict__ Abt,
    const int* __restrict__ ordp, const float* __restrict__ prp,
    float dem, float& before, float& objp, float& slackv)
{
    float cap[N];
    int   gg[N];
#pragma unroll
    for (int j = 0; j < N; ++j) {
        int g = ordp[k0 + j];
        gg[j] = g;
        int gl = (g < G_) ? g : 0;             // slack slot: safe dummy load
        cap[j] = Rbt[(size_t)gl * T_];
    }
#pragma unroll
    for (int j = 0; j < N; ++j) {
        int g = gg[j];
        float c = (g == G_) ? dem : cap[j];
        float a = fminf(fmaxf(dem - before, 0.f), c);
        before += c;
        objp = fmaf(prp[k0 + j], a, objp);
        if (g == G_) slackv = a;
        else         Abt[(size_t)g * T_] = a;  // independent; never waited on
    }
}

__global__ __launch_bounds__(BLOCK, 3) void dispatch_kernel(
    const float* __restrict__ R_up, const float* __restrict__ R_dn,
    const float* __restrict__ omega, const float* __restrict__ b_G,
    const float* __restrict__ voll, const float* __restrict__ vosp,
    const float* __restrict__ ru, const float* __restrict__ rd,
    float* __restrict__ out, int B)
{
    __shared__ float s_praw[2][GP1];
    __shared__ int   s_ord[2][GP1];
    __shared__ float s_pr[2][GP1];
    __shared__ float s_obj[BLOCK];

    const int tid = threadIdx.x;

    // ---- per-block redundant sort (prices depend only on b_G + scalars) ----
    if (tid < GP1) {
        if (tid < G_) {
            float bg = b_G[tid];
            s_praw[0][tid] = ru[0] * bg;       // c_up
            s_praw[1][tid] = rd[0] * bg;       // c_dn
        } else {
            s_praw[0][tid] = voll[0];
            s_praw[1][tid] = vosp[0];
        }
    }
    __syncthreads();
    if (tid < GP1) {
        float mu = s_praw[0][tid], md = s_praw[1][tid];
        int r0 = 0, r1 = 0;
        for (int j = 0; j < GP1; ++j) {
            float vu = s_praw[0][j], vd = s_praw[1][j];
            r0 += (vu < mu) || (vu == mu && j < tid);   // stable == jnp.argsort
            r1 += (vd < md) || (vd == md && j < tid);
        }
        s_ord[0][r0] = tid; s_pr[0][r0] = mu;
        s_ord[1][r1] = tid; s_pr[1][r1] = md;
    }
    __syncthreads();

    // ---- thread mapping: pass p, batch b, time t ----
    const int p     = tid / (BPB * T_);        // 0 = up, 1 = dn
    const int local = tid - p * (BPB * T_);
    const int bb    = local / T_;
    const int t     = local - bb * T_;
    const int b     = blockIdx.x * BPB + bb;

    const size_t bgt = (size_t)B * G_ * T_;
    const float* __restrict__ R = p ? R_dn : R_up;
    const float* __restrict__ Rbt = R + (size_t)b * (G_ * T_) + t;
    float* __restrict__ Abt = out + (size_t)p * bgt + (size_t)b * (G_ * T_) + t;
    float* __restrict__ slack_out = out + 2 * bgt + (size_t)p * B * T_ + (size_t)b * T_ + t;
    float* __restrict__ obj_out   = out + 2 * bgt + 2 * (size_t)B * T_;

    const float om  = omega[(size_t)b * T_ + t];
    const float dem = p ? fmaxf(-om, 0.f) : fmaxf(om, 0.f);

    const int* __restrict__ ordp = s_ord[p];
    const float* __restrict__ prp = s_pr[p];

    float before = 0.f, objp = 0.f, slackv = 0.f;
    chunk<32>( 0, Rbt, Abt, ordp, prp, dem, before, objp, slackv);
    chunk<32>(32, Rbt, Abt, ordp, prp, dem, before, objp, slackv);
    chunk<32>(64, Rbt, Abt, ordp, prp, dem, before, objp, slackv);
    chunk< 5>(96, Rbt, Abt, ordp, prp, dem, before, objp, slackv);

    *slack_out = slackv;

    // ---- rt_obj: block holds all (pass, t) terms for its 4 b's -> plain store
    s_obj[tid] = objp;
    __syncthreads();
    if (tid < BPB) {
        float s = 0.f;
        for (int j = 0; j < T_; ++j)
            s += s_obj[tid * T_ + j] + s_obj[BPB * T_ + tid * T_ + j];
        obj_out[blockIdx.x * BPB + tid] = s;
    }
}

extern "C" void kernel_launch(void* const* d_in, const int* in_sizes, int n_in,
                              void* d_out, int out_size, void* d_ws, size_t ws_size,
                              hipStream_t stream)
{
    const float* R_up  = (const float*)d_in[0];
    const float* R_dn  = (const float*)d_in[1];
    const float* omega = (const float*)d_in[2];
    const float* b_G   = (const float*)d_in[3];
    const float* voll  = (const float*)d_in[4];
    const float* vosp  = (const float*)d_in[5];
    const float* ru    = (const float*)d_in[6];
    const float* rd    = (const float*)d_in[7];

    const int B = in_sizes[0] / (G_ * T_);
    float* out = (float*)d_out;

    dispatch_kernel<<<B / BPB, BLOCK, 0, stream>>>(
        R_up, R_dn, omega, b_G, voll, vosp, ru, rd, out, B);
}

// Round 4
// 189.205 us; speedup vs baseline: 1.2273x; 1.2273x over previous
//
#include <hip/hip_runtime.h>

#define G_ 100
#define T_ 24
#define GP1 101
#define NB 4                      // b's per block (block does BOTH passes)
#define BLOCK 256
#define TILE (G_ * T_)            // 2400 floats per (b,pass)
#define VPB (TILE / 4)            // 600 float4 per b
#define TSTRIDE 2416              // padded b-stride in floats (mod 32 == 16)
#define PASS_F (NB * TSTRIDE)     // per-pass LDS floats (mod 32 == 0)
#define NVEC 19                   // ceil(2*NB*VPB / BLOCK) = ceil(4800/256)
#define NACT (2 * NB * T_)        // 192 scan-active threads

typedef float vfloat4 __attribute__((ext_vector_type(4)));  // native vec for builtins

// Batched in-LDS merit-order chunk: prefetch order/price, batch the LDS cap
// reads, then the serial clip-scan writing alloc in-place over cap.
template<int N>
__device__ __forceinline__ void scan_chunk(int k0,
    float* __restrict__ tile, const int* __restrict__ ordp,
    const float* __restrict__ prp, float dem,
    float& before, float& objp, float& slackv)
{
    int gg[N]; float pr[N], cap[N];
#pragma unroll
    for (int j = 0; j < N; ++j) { gg[j] = ordp[k0 + j]; pr[j] = prp[k0 + j]; }
#pragma unroll
    for (int j = 0; j < N; ++j) {
        int gl = (gg[j] < G_) ? gg[j] : 0;      // slack slot: safe dummy read
        cap[j] = tile[gl * T_];
    }
#pragma unroll
    for (int j = 0; j < N; ++j) {
        float c = (gg[j] == G_) ? dem : cap[j];
        float a = fminf(fmaxf(dem - before, 0.f), c);
        before += c;
        objp = fmaf(pr[j], a, objp);
        if (gg[j] == G_) slackv = a;
        else             tile[gg[j] * T_] = a;  // in-place: each g touched once
    }
}

__global__ __launch_bounds__(BLOCK, 2) void dispatch_kernel(
    const float* __restrict__ R_up, const float* __restrict__ R_dn,
    const float* __restrict__ omega, const float* __restrict__ b_G,
    const float* __restrict__ voll, const float* __restrict__ vosp,
    const float* __restrict__ ru, const float* __restrict__ rd,
    float* __restrict__ out, int B)
{
    __shared__ float s_tile[2 * PASS_F];        // 77312 B, in-place cap->alloc
    __shared__ float s_praw[2][GP1];
    __shared__ int   s_ord[2][GP1];
    __shared__ float s_pr[2][GP1];
    __shared__ float s_obj[NACT];

    const int tid = threadIdx.x;
    const int b0  = blockIdx.x * NB;
    const size_t bgt = (size_t)B * TILE;

    // ---- price vectors (tiny) ----
    if (tid < GP1) {
        if (tid < G_) {
            float bg = b_G[tid];
            s_praw[0][tid] = ru[0] * bg;        // c_up
            s_praw[1][tid] = rd[0] * bg;        // c_dn
        } else {
            s_praw[0][tid] = voll[0];
            s_praw[1][tid] = vosp[0];
        }
    }
    __syncthreads();

    // ---- issue all tile loads (coalesced float4 streams) into registers ----
    vfloat4 buf[NVEC];
#pragma unroll
    for (int j = 0; j < NVEC; ++j) {
        int i = tid + j * BLOCK;
        if (i < 2 * NB * VPB) {
            int pass = i / (NB * VPB);
            int rem  = i - pass * (NB * VPB);
            int bb   = rem / VPB;
            int v    = rem - bb * VPB;
            const vfloat4* src = pass ? (const vfloat4*)R_dn : (const vfloat4*)R_up;
            buf[j] = src[(size_t)(b0 + bb) * VPB + v];
        }
    }

    // scan-thread mapping + omega load (independent; overlaps load latency)
    const int p    = tid / (NB * T_);           // 0 = up, 1 = dn
    const int rm   = tid - p * (NB * T_);
    const int bb_s = rm / T_;
    const int t    = rm - bb_s * T_;
    float om = 0.f;
    if (tid < NACT) om = omega[(size_t)(b0 + bb_s) * T_ + t];

    // ---- stable rank-sort (VALU; overlaps the in-flight loads) ----
    if (tid < GP1) {
        float mu = s_praw[0][tid], md = s_praw[1][tid];
        int r0 = 0, r1 = 0;
        for (int j = 0; j < GP1; ++j) {
            float vu = s_praw[0][j], vd = s_praw[1][j];
            r0 += (vu < mu) || (vu == mu && j < tid);   // == jnp.argsort stable
            r1 += (vd < md) || (vd == md && j < tid);
        }
        s_ord[0][r0] = tid; s_pr[0][r0] = mu;
        s_ord[1][r1] = tid; s_pr[1][r1] = md;
    }

    // ---- registers -> LDS tiles (padded b-stride) ----
#pragma unroll
    for (int j = 0; j < NVEC; ++j) {
        int i = tid + j * BLOCK;
        if (i < 2 * NB * VPB) {
            int pass = i / (NB * VPB);
            int rem  = i - pass * (NB * VPB);
            int bb   = rem / VPB;
            int v    = rem - bb * VPB;
            *(vfloat4*)&s_tile[pass * PASS_F + bb * TSTRIDE + v * 4] = buf[j];
        }
    }
    __syncthreads();

    // ---- merit-order scan, entirely in LDS ----
    if (tid < NACT) {
        const float dem = p ? fmaxf(-om, 0.f) : fmaxf(om, 0.f);
        float* __restrict__ tile = &s_tile[p * PASS_F + bb_s * TSTRIDE + t];
        const int*   __restrict__ ordp = s_ord[p];
        const float* __restrict__ prp  = s_pr[p];
        float before = 0.f, objp = 0.f, slackv = 0.f;
        scan_chunk<16>( 0, tile, ordp, prp, dem, before, objp, slackv);
        scan_chunk<16>(16, tile, ordp, prp, dem, before, objp, slackv);
        scan_chunk<16>(32, tile, ordp, prp, dem, before, objp, slackv);
        scan_chunk<16>(48, tile, ordp, prp, dem, before, objp, slackv);
        scan_chunk<16>(64, tile, ordp, prp, dem, before, objp, slackv);
        scan_chunk<16>(80, tile, ordp, prp, dem, before, objp, slackv);
        scan_chunk< 5>(96, tile, ordp, prp, dem, before, objp, slackv);

        out[2 * bgt + (size_t)p * B * T_ + (size_t)(b0 + bb_s) * T_ + t] = slackv;
        s_obj[tid] = objp;
    }
    __syncthreads();

    // ---- rt_obj: complete per block (both passes) -> plain store ----
    if (tid < NB) {
        float s = 0.f;
        for (int j = 0; j < T_; ++j)
            s += s_obj[tid * T_ + j] + s_obj[NB * T_ + tid * T_ + j];
        out[2 * bgt + 2 * (size_t)B * T_ + b0 + tid] = s;
    }

    // ---- LDS -> global, coalesced nontemporal float4 streams ----
#pragma unroll
    for (int j = 0; j < NVEC; ++j) {
        int i = tid + j * BLOCK;
        if (i < 2 * NB * VPB) {
            int pass = i / (NB * VPB);
            int rem  = i - pass * (NB * VPB);
            int bb   = rem / VPB;
            int v    = rem - bb * VPB;
            vfloat4 val = *(const vfloat4*)&s_tile[pass * PASS_F + bb * TSTRIDE + v * 4];
            vfloat4* dst = (vfloat4*)(out + (size_t)pass * bgt + (size_t)(b0 + bb) * TILE) + v;
            __builtin_nontemporal_store(val, dst);
        }
    }
}

extern "C" void kernel_launch(void* const* d_in, const int* in_sizes, int n_in,
                              void* d_out, int out_size, void* d_ws, size_t ws_size,
                              hipStream_t stream)
{
    const float* R_up  = (const float*)d_in[0];
    const float* R_dn  = (const float*)d_in[1];
    const float* omega = (const float*)d_in[2];
    const float* b_G   = (const float*)d_in[3];
    const float* voll  = (const float*)d_in[4];
    const float* vosp  = (const float*)d_in[5];
    const float* ru    = (const float*)d_in[6];
    const float* rd    = (const float*)d_in[7];

    const int B = in_sizes[0] / TILE;
    float* out = (float*)d_out;

    dispatch_kernel<<<B / NB, BLOCK, 0, stream>>>(
        R_up, R_dn, omega, b_G, voll, vosp, ru, rd, out, B);
}